// Round 6
// baseline (471.864 us; speedup 1.0000x reference)
//
#include <hip/hip_runtime.h>

typedef unsigned short ushort_t;
typedef __bf16  bf16x8 __attribute__((ext_vector_type(8)));
typedef float   f32x4  __attribute__((ext_vector_type(4)));
typedef unsigned short u16x8 __attribute__((ext_vector_type(8)));

#define MFMA16(a,b,c) __builtin_amdgcn_mfma_f32_16x16x32_bf16((a),(b),(c),0,0,0)

static __device__ __forceinline__ ushort_t f2bf(float f){
  __bf16 h = (__bf16)f;
  return __builtin_bit_cast(ushort_t, h);
}
static __device__ __forceinline__ float bf2f(ushort_t b){
  union{unsigned u; float f;} x; x.u = ((unsigned)b)<<16; return x.f;
}
static __device__ __forceinline__ bf16x8 ldg_bf8(const ushort_t* p, bool valid){
  u16x8 r = {0,0,0,0,0,0,0,0};
  if(valid) r = *(const u16x8*)p;
  return __builtin_bit_cast(bf16x8, r);
}
static __device__ __forceinline__ bf16x8 ldg_bf8u(const ushort_t* p){
  u16x8 r = *(const u16x8*)p;
  return __builtin_bit_cast(bf16x8, r);
}
static __device__ __forceinline__ bf16x8 lds_bf8(const ushort_t* p){
  u16x8 r = *(const u16x8*)p;
  return __builtin_bit_cast(bf16x8, r);
}
// async global->LDS, 16B per lane; lds dst must be wave-uniform base + lane*16
static __device__ __forceinline__ void gload_lds16(const ushort_t* g, ushort_t* l){
  __builtin_amdgcn_global_load_lds(
      (const __attribute__((address_space(1))) void*)g,
      (__attribute__((address_space(3))) void*)l, 16, 0, 0);
}

// ---------------------------------------------------------------- prep
// qkvT[n(768)][k(192)]
// wlT: [tap(9)][ks(8)][col(256)][sl(4)][j(8)], XOR-swizzle baked
// woT[n(192)][k(256)]
// xbf: bf16 x, 100352x192, chunk-swizzle baked: xbf[row][cp] = x[row][cp^(row&7)]
__global__ __launch_bounds__(256) void prep_kernel(
    const float* __restrict__ x,
    const float* __restrict__ Wq, const float* __restrict__ Wk,
    const float* __restrict__ Wv, const float* __restrict__ Wl,
    const float* __restrict__ Wo,
    ushort_t* __restrict__ qkvT, ushort_t* __restrict__ wlT,
    ushort_t* __restrict__ woT, ushort_t* __restrict__ xbf)
{
  int idx = blockIdx.x*256 + threadIdx.x;
  if(idx < 147456){
    int n = idx/192, kk = idx%192;
    const float* W = (n < 256) ? Wq : ((n < 512) ? Wk : Wv);
    qkvT[idx] = f2bf(W[kk*256 + (n & 255)]);
  } else if(idx < 147456 + 589824){
    int t2 = idx - 147456;
    int j   = t2 & 7;
    int sl  = (t2 >> 3) & 3;
    int col = (t2 >> 5) & 255;
    int ks  = (t2 >> 13) & 7;
    int tap = t2 >> 16;
    int grp = sl ^ ((col>>1)&3);
    int k = ks*32 + grp*8 + j;
    wlT[t2] = f2bf(Wl[((size_t)tap*256 + k)*256 + col]);
  } else if(idx < 737280 + 49152){
    int t3 = idx - 737280;
    int col = t3/256, kk = t3%256;
    woT[t3] = f2bf(Wo[kk*192 + col]);
  } else {
    int c = idx - 786432;               // chunk id, 100352*24 chunks
    int row = c/24, cp = c%24;
    int sc = cp ^ (row&7);
    const float* src = x + (size_t)row*192 + sc*8;
    float4 f0 = *(const float4*)src;
    float4 f1 = *(const float4*)(src+4);
    u16x8 o;
    o[0]=f2bf(f0.x); o[1]=f2bf(f0.y); o[2]=f2bf(f0.z); o[3]=f2bf(f0.w);
    o[4]=f2bf(f1.x); o[5]=f2bf(f1.y); o[6]=f2bf(f1.z); o[7]=f2bf(f1.w);
    *(u16x8*)&xbf[(size_t)c*8] = o;
  }
}

// ---------------------------------------------------------------- qkv GEMM
// C[100352,256] = X[100352,192] @ W[192,256]  (per which in {q,k,v})
// block: 64px x 256col, 4 waves (1m x 4n), wave 64x64. A staged via linear
// global_load_lds DMA from pre-swizzled xbf; 24 KB LDS -> high occupancy.
__global__ __launch_bounds__(256,4) void qkv_kernel(
    const ushort_t* __restrict__ xbf, const ushort_t* __restrict__ WT,
    ushort_t* __restrict__ q, ushort_t* __restrict__ kbuf,
    ushort_t* __restrict__ vbuf)
{
  __shared__ ushort_t aLds[64*192];     // 24 KB
  const int m0 = blockIdx.x * 64;
  const int which = blockIdx.y;
  ushort_t* O = (which==0) ? q : ((which==1) ? kbuf : vbuf);
  const int tid = threadIdx.x;
  const int l = tid & 63, w = tid >> 6;
  const int lr = l&15, g = l>>4;
  // stage A: pure linear copy (swizzle pre-baked in xbf)
  #pragma unroll
  for(int r=0;r<6;++r){
    gload_lds16(xbf + (size_t)m0*192 + (size_t)(tid + r*256)*8,
                aLds + (size_t)(r*256 + w*64)*8);
  }
  __syncthreads();

  const ushort_t* Wbase = WT + (size_t)(which*256 + w*64)*192;
  f32x4 acc[4][4];
  #pragma unroll
  for(int mi=0;mi<4;++mi)
    #pragma unroll
    for(int nj=0;nj<4;++nj){ f32x4 z={0.f,0.f,0.f,0.f}; acc[mi][nj]=z; }

  bf16x8 bA[4], bB[4];
  #pragma unroll
  for(int nj=0;nj<4;++nj) bA[nj] = ldg_bf8u(Wbase + (size_t)(nj*16+lr)*192 + g*8);

  #pragma unroll
  for(int ks2=0; ks2<3; ++ks2){
    int ks0 = 2*ks2, ks1 = 2*ks2+1;
    #pragma unroll
    for(int nj=0;nj<4;++nj) bB[nj] = ldg_bf8u(Wbase + (size_t)(nj*16+lr)*192 + ks1*32 + g*8);
    #pragma unroll
    for(int mi=0;mi<4;++mi){
      int row = mi*16 + lr;
      bf16x8 af = lds_bf8(&aLds[(row*192 + ks0*32 + g*8) ^ ((row&7)<<3)]);
      #pragma unroll
      for(int nj=0;nj<4;++nj) acc[mi][nj] = MFMA16(af, bA[nj], acc[mi][nj]);
    }
    if(ks2<2){
      #pragma unroll
      for(int nj=0;nj<4;++nj) bA[nj] = ldg_bf8u(Wbase + (size_t)(nj*16+lr)*192 + (ks1+1)*32 + g*8);
    }
    #pragma unroll
    for(int mi=0;mi<4;++mi){
      int row = mi*16 + lr;
      bf16x8 af = lds_bf8(&aLds[(row*192 + ks1*32 + g*8) ^ ((row&7)<<3)]);
      #pragma unroll
      for(int nj=0;nj<4;++nj) acc[mi][nj] = MFMA16(af, bB[nj], acc[mi][nj]);
    }
  }
  #pragma unroll
  for(int mi=0;mi<4;++mi)
    #pragma unroll
    for(int nj=0;nj<4;++nj){
      int col = w*64 + nj*16 + lr;
      #pragma unroll
      for(int i=0;i<4;++i){
        int row = mi*16 + g*4 + i;
        O[(size_t)(m0+row)*256 + col] = f2bf(acc[mi][nj][i]);
      }
    }
}

// ---------------------------------------------------------------- 3x3 conv
// implicit GEMM, 128px x 256ch per block, 4 waves (2m x 2n), wave 64x128.
// A (shifted-pixel tile) double-buffered in LDS, one barrier per ks (8 total).
// B (weights, L2-resident) lives in REGISTERS: 8 bf16x8 fragments per wave,
// register double-buffered one tap ahead. No B LDS, no per-tap barriers.
__global__ __launch_bounds__(256,2) void conv_kernel(
    const ushort_t* __restrict__ v, const ushort_t* __restrict__ WlT,
    const float* __restrict__ b_local, ushort_t* __restrict__ local_out)
{
  __shared__ ushort_t aBuf[2][256*32];   // 2 x 16 KB
  const int bid = blockIdx.x;
  const int tile = (bid & 7) * 98 + (bid >> 3);   // XCD-contiguous (784 = 8*98)
  const int p0 = tile * 128;
  const int tid = threadIdx.x;
  const int l = tid&63, w=tid>>6, wm=w>>1, wn=w&1, lr=l&15, g=l>>4;

  unsigned maskbits[4];
  int pxloc[4];
  #pragma unroll
  for(int mi=0;mi<4;++mi){
    int p = p0 + wm*64 + mi*16 + lr;
    int rem = p % 3136;
    int y = rem/56, x = rem%56;
    unsigned mb = 0;
    #pragma unroll
    for(int tap=0;tap<9;++tap){
      int dy = tap/3 - 1, dx = tap%3 - 1;
      if(((unsigned)(y+dy) < 56u) && ((unsigned)(x+dx) < 56u)) mb |= (1u<<tap);
    }
    maskbits[mi] = mb;
    pxloc[mi] = wm*64 + mi*16 + lr + 64;
  }

  // loop-invariant per-lane B offsets (elements) for the 8 nj fragments
  unsigned bOff[8];
  #pragma unroll
  for(int nj=0;nj<8;++nj){
    int col = wn*128 + nj*16 + lr;
    int slb = g ^ ((col>>1)&3);
    bOff[nj] = col*32 + slb*8;
  }

  auto stageA = [&](int ks, ushort_t* dst){
    #pragma unroll
    for(int r=0;r<4;++r){
      int c = tid + r*256;
      int px = c>>2, sl = c&3;
      int px_abs = p0 - 64 + px;
      px_abs = min(max(px_abs, 0), 100351);
      int chunk = sl ^ ((px>>1)&3);
      gload_lds16(v + (size_t)px_abs*256 + ks*32 + chunk*8,
                  dst + (size_t)(r*256 + w*64)*8);
    }
  };

  f32x4 acc[4][8];
  #pragma unroll
  for(int mi=0;mi<4;++mi)
    #pragma unroll
    for(int nj=0;nj<8;++nj){ f32x4 z={0.f,0.f,0.f,0.f}; acc[mi][nj]=z; }

  bf16x8 bCur[8], bNxt[8];
  // preload B(ks=0, tap=0)
  #pragma unroll
  for(int nj=0;nj<8;++nj) bCur[nj] = ldg_bf8u(WlT + bOff[nj]);
  #pragma unroll
  for(int nj=0;nj<8;++nj) bNxt[nj] = bCur[nj];
  stageA(0, aBuf[0]);

  for(int ks=0; ks<8; ++ks){
    __syncthreads();                   // drains: A(ks) + B(ks,0) ready
    const ushort_t* aL = aBuf[ks&1];
    const ushort_t* Bks = WlT + (size_t)ks*8192;
    #pragma unroll
    for(int tap=0; tap<9; ++tap){
      // prefetch next tap's B fragments (next ks' tap0 at tap==8)
      if(tap < 8){
        #pragma unroll
        for(int nj=0;nj<8;++nj)
          bNxt[nj] = ldg_bf8u(Bks + (size_t)(tap+1)*65536 + bOff[nj]);
      } else if(ks < 7){
        #pragma unroll
        for(int nj=0;nj<8;++nj)
          bNxt[nj] = ldg_bf8u(Bks + 8192 + bOff[nj]);   // (ks+1, tap0)
      }
      if(tap==7 && ks<7) stageA(ks+1, aBuf[(ks+1)&1]);
      // compute with bCur
      int shift = (tap/3 - 1)*56 + (tap%3 - 1);
      bf16x8 af[4];
      #pragma unroll
      for(int mi=0;mi<4;++mi){
        int px = pxloc[mi] + shift;
        int sl = g ^ ((px>>1)&3);
        u16x8 rv = *(const u16x8*)&aL[px*32 + sl*8];
        if(!((maskbits[mi]>>tap)&1)){ u16x8 z={0,0,0,0,0,0,0,0}; rv=z; }
        af[mi] = __builtin_bit_cast(bf16x8, rv);
      }
      __builtin_amdgcn_s_setprio(1);
      #pragma unroll
      for(int nj=0;nj<8;++nj)
        #pragma unroll
        for(int mi=0;mi<4;++mi) acc[mi][nj] = MFMA16(af[mi], bCur[nj], acc[mi][nj]);
      __builtin_amdgcn_s_setprio(0);
      #pragma unroll
      for(int nj=0;nj<8;++nj) bCur[nj] = bNxt[nj];
    }
  }

  // epilogue
  #pragma unroll
  for(int nj=0;nj<8;++nj){
    int col = wn*128 + nj*16 + lr;
    float bb = b_local[col];
    #pragma unroll
    for(int mi=0;mi<4;++mi)
      #pragma unroll
      for(int i=0;i<4;++i){
        int p = p0 + wm*64 + mi*16 + g*4 + i;
        local_out[(size_t)p*256 + col] = f2bf(acc[mi][nj][i] + bb);
      }
  }
}

// ---------------------------------------------------------------- attention
// one wave per (window, head); 49 padded to 64
__global__ __launch_bounds__(256) void attn_kernel(
    const ushort_t* __restrict__ q, const ushort_t* __restrict__ k,
    const ushort_t* __restrict__ v, ushort_t* __restrict__ out)
{
  __shared__ ushort_t pLds[4*64*64];
  __shared__ ushort_t vLds[4*32*64];
  const int tid = threadIdx.x;
  const int w = tid>>6, l = tid&63, lr = l&15, g = l>>4;
  const int gid = blockIdx.x*4 + w;
  const int win = gid>>3, head = gid&7;
  const int b = win>>6, rem = win&63, wy = rem>>3, wx = rem&7;
  const size_t base = (size_t)b*3136 + wy*7*56 + wx*7;
  ushort_t* pl = pLds + w*4096;
  ushort_t* vl = vLds + w*2048;
  {
    int p = l;
    bool valid = p < 49;
    const ushort_t* vp = v + (base + (p/7)*56 + (p%7))*256 + head*32;
    #pragma unroll
    for(int d0=0; d0<32; d0+=8){
      u16x8 rv = {0,0,0,0,0,0,0,0};
      if(valid) rv = *(const u16x8*)(vp + d0);
      #pragma unroll
      for(int j=0;j<8;++j){
        int d = d0+j;
        vl[(d*64 + p) ^ ((d&7)<<3)] = valid ? rv[j] : (ushort_t)0;
      }
    }
  }
  f32x4 dot[4][4];
  #pragma unroll
  for(int mi=0;mi<4;++mi)
    #pragma unroll
    for(int nj=0;nj<4;++nj){ f32x4 z={0.f,0.f,0.f,0.f}; dot[mi][nj]=z; }
  bf16x8 qf[4], kf[4];
  #pragma unroll
  for(int t=0;t<4;++t){
    int p = t*16 + lr; bool valid = p<49;
    size_t pix = base + (p/7)*56 + (p%7);
    qf[t] = ldg_bf8(q + pix*256 + head*32 + g*8, valid);
    kf[t] = ldg_bf8(k + pix*256 + head*32 + g*8, valid);
  }
  #pragma unroll
  for(int mi=0;mi<4;++mi)
    #pragma unroll
    for(int nj=0;nj<4;++nj)
      dot[mi][nj] = MFMA16(qf[mi], kf[nj], dot[mi][nj]);
  const float sc = 0.17677669529663687f * 1.4426950408889634f;
  float rs[4][4];
  #pragma unroll
  for(int mi=0;mi<4;++mi){
    #pragma unroll
    for(int i=0;i<4;++i){
      float m = -1e30f;
      #pragma unroll
      for(int nj=0;nj<4;++nj){
        int col = nj*16 + lr;
        if(col < 49) m = fmaxf(m, dot[mi][nj][i]);
      }
      m = fmaxf(m, __shfl_xor(m,1));
      m = fmaxf(m, __shfl_xor(m,2));
      m = fmaxf(m, __shfl_xor(m,4));
      m = fmaxf(m, __shfl_xor(m,8));
      float e[4]; float s = 0.f;
      #pragma unroll
      for(int nj=0;nj<4;++nj){
        int col = nj*16 + lr;
        e[nj] = (col < 49) ? exp2f((dot[mi][nj][i]-m)*sc) : 0.f;
        s += e[nj];
      }
      s += __shfl_xor(s,1); s += __shfl_xor(s,2);
      s += __shfl_xor(s,4); s += __shfl_xor(s,8);
      rs[mi][i] = s;
      int row = mi*16 + g*4 + i;
      #pragma unroll
      for(int nj=0;nj<4;++nj){
        int col = nj*16 + lr;
        pl[(row*64 + col) ^ ((row&7)<<3)] = f2bf(e[nj]);
      }
    }
  }
  __syncthreads();
  f32x4 o[4][2];
  #pragma unroll
  for(int mi=0;mi<4;++mi)
    #pragma unroll
    for(int nj=0;nj<2;++nj){ f32x4 z={0.f,0.f,0.f,0.f}; o[mi][nj]=z; }
  #pragma unroll
  for(int ks=0;ks<2;++ks){
    bf16x8 pa[4];
    #pragma unroll
    for(int mi=0;mi<4;++mi){
      int row = mi*16 + lr;
      pa[mi] = lds_bf8(&pl[(row*64 + ks*32 + g*8) ^ ((row&7)<<3)]);
    }
    #pragma unroll
    for(int nj=0;nj<2;++nj){
      int d = nj*16 + lr;
      bf16x8 vb = lds_bf8(&vl[(d*64 + ks*32 + g*8) ^ ((d&7)<<3)]);
      #pragma unroll
      for(int mi=0;mi<4;++mi) o[mi][nj] = MFMA16(pa[mi], vb, o[mi][nj]);
    }
  }
  #pragma unroll
  for(int mi=0;mi<4;++mi){
    #pragma unroll
    for(int i=0;i<4;++i){
      int row = mi*16 + g*4 + i;
      if(row < 49){
        size_t pix = base + (row/7)*56 + (row%7);
        float inv = 1.0f / rs[mi][i];
        #pragma unroll
        for(int nj=0;nj<2;++nj){
          out[pix*256 + head*32 + nj*16 + lr] = f2bf(o[mi][nj][i] * inv);
        }
      }
    }
  }
}

// ---------------------------------------------------------------- out proj
__global__ __launch_bounds__(256) void outproj_kernel(
    const ushort_t* __restrict__ attn, const ushort_t* __restrict__ local,
    const ushort_t* __restrict__ WoT, const float* __restrict__ b_out,
    float* __restrict__ out)
{
  __shared__ ushort_t aLds[128*256];
  const int m0 = blockIdx.x*128;
  const int tid = threadIdx.x;
  #pragma unroll
  for(int it=0; it<16; ++it){
    int c = tid + it*256;
    int row = c >> 5, cc = c & 31;
    size_t off = (size_t)(m0+row)*256 + cc*8;
    u16x8 a = *(const u16x8*)(attn + off);
    u16x8 bl = *(const u16x8*)(local + off);
    u16x8 o;
    #pragma unroll
    for(int j=0;j<8;++j) o[j] = f2bf(bf2f(a[j]) + bf2f(bl[j]));
    *(u16x8*)&aLds[(row*256 + cc*8) ^ ((row&7)<<3)] = o;
  }
  __syncthreads();
  const int l = tid&63, w = tid>>6, wm=w>>1, wn=w&1, lr=l&15, g=l>>4;
  f32x4 acc[4][6];
  #pragma unroll
  for(int mi=0;mi<4;++mi)
    #pragma unroll
    for(int nj=0;nj<6;++nj){ f32x4 z={0.f,0.f,0.f,0.f}; acc[mi][nj]=z; }
  #pragma unroll
  for(int ks=0;ks<8;++ks){
    bf16x8 af[4];
    #pragma unroll
    for(int mi=0;mi<4;++mi){
      int row = wm*64 + mi*16 + lr;
      af[mi] = lds_bf8(&aLds[(row*256 + ks*32 + g*8) ^ ((row&7)<<3)]);
    }
    #pragma unroll
    for(int nj=0;nj<6;++nj){
      int col = wn*96 + nj*16 + lr;
      bf16x8 bfr = ldg_bf8u(WoT + (size_t)col*256 + ks*32 + g*8);
      #pragma unroll
      for(int mi=0;mi<4;++mi) acc[mi][nj] = MFMA16(af[mi], bfr, acc[mi][nj]);
    }
  }
  #pragma unroll
  for(int nj=0;nj<6;++nj){
    int col = wn*96 + nj*16 + lr;
    float bb = b_out[col];
    #pragma unroll
    for(int mi=0;mi<4;++mi)
      #pragma unroll
      for(int i=0;i<4;++i){
        int row = wm*64 + mi*16 + g*4 + i;
        out[(size_t)(m0+row)*192 + col] = acc[mi][nj][i] + bb;
      }
  }
}

extern "C" void kernel_launch(void* const* d_in, const int* in_sizes, int n_in,
                              void* d_out, int out_size, void* d_ws, size_t ws_size,
                              hipStream_t stream)
{
  const float* x  = (const float*)d_in[0];
  const float* Wq = (const float*)d_in[1];
  const float* Wk = (const float*)d_in[2];
  const float* Wv = (const float*)d_in[3];
  const float* Wl = (const float*)d_in[4];
  const float* bl = (const float*)d_in[5];
  const float* Wo = (const float*)d_in[6];
  const float* bo = (const float*)d_in[7];
  float* out = (float*)d_out;
  char* ws = (char*)d_ws;
  ushort_t* q    = (ushort_t*)(ws);
  ushort_t* kbuf = (ushort_t*)(ws + 51380224);
  ushort_t* vbuf = (ushort_t*)(ws + 102760448);
  ushort_t* attn = (ushort_t*)(ws + 154140672);  // also xbf (dead before attn_kernel)
  ushort_t* locl = (ushort_t*)(ws + 205520896);
  ushort_t* qkvT = (ushort_t*)(ws + 256901120);
  ushort_t* wlT  = (ushort_t*)(ws + 257196032);
  ushort_t* woT  = (ushort_t*)(ws + 258375680);
  ushort_t* xbf  = attn;   // 38.5 MB < 51.4 MB slot

  prep_kernel<<<12480, 256, 0, stream>>>(x, Wq, Wk, Wv, Wl, Wo, qkvT, wlT, woT, xbf);
  qkv_kernel<<<dim3(1568,3), 256, 0, stream>>>(xbf, qkvT, q, kbuf, vbuf);
  conv_kernel<<<784, 256, 0, stream>>>(vbuf, wlT, bl, locl);
  attn_kernel<<<4096, 256, 0, stream>>>(q, kbuf, vbuf, attn);
  outproj_kernel<<<784, 256, 0, stream>>>(attn, locl, woT, bo, out);
}

// Round 7
// 336.943 us; speedup vs baseline: 1.4004x; 1.4004x over previous
//
#include <hip/hip_runtime.h>

typedef unsigned short ushort_t;
typedef __bf16  bf16x8 __attribute__((ext_vector_type(8)));
typedef float   f32x4  __attribute__((ext_vector_type(4)));
typedef unsigned short u16x8 __attribute__((ext_vector_type(8)));

#define MFMA16(a,b,c) __builtin_amdgcn_mfma_f32_16x16x32_bf16((a),(b),(c),0,0,0)
#define WAITVM(N) asm volatile("s_waitcnt vmcnt(" #N ")" ::: "memory")
#define BARRIER() do{ __builtin_amdgcn_s_barrier(); asm volatile("" ::: "memory"); }while(0)

static __device__ __forceinline__ ushort_t f2bf(float f){
  __bf16 h = (__bf16)f;
  return __builtin_bit_cast(ushort_t, h);
}
static __device__ __forceinline__ float bf2f(ushort_t b){
  union{unsigned u; float f;} x; x.u = ((unsigned)b)<<16; return x.f;
}
static __device__ __forceinline__ bf16x8 ldg_bf8(const ushort_t* p, bool valid){
  u16x8 r = {0,0,0,0,0,0,0,0};
  if(valid) r = *(const u16x8*)p;
  return __builtin_bit_cast(bf16x8, r);
}
static __device__ __forceinline__ bf16x8 ldg_bf8u(const ushort_t* p){
  u16x8 r = *(const u16x8*)p;
  return __builtin_bit_cast(bf16x8, r);
}
static __device__ __forceinline__ bf16x8 lds_bf8(const ushort_t* p){
  u16x8 r = *(const u16x8*)p;
  return __builtin_bit_cast(bf16x8, r);
}
// async global->LDS, 16B per lane; lds dst must be wave-uniform base + lane*16
static __device__ __forceinline__ void gload_lds16(const ushort_t* g, ushort_t* l){
  __builtin_amdgcn_global_load_lds(
      (const __attribute__((address_space(1))) void*)g,
      (__attribute__((address_space(3))) void*)l, 16, 0, 0);
}

// ---------------------------------------------------------------- prep
// qkvT[n(768)][k(192)]
// wlT: [tap(9)][ks(8)][col(256)][sl(4)][j(8)], XOR-swizzle baked
// woT[n(192)][k(256)]
// xbf: bf16 x, 100352x192, chunk-swizzle baked: xbf[row][cp] = x[row][cp^(row&7)]
__global__ __launch_bounds__(256) void prep_kernel(
    const float* __restrict__ x,
    const float* __restrict__ Wq, const float* __restrict__ Wk,
    const float* __restrict__ Wv, const float* __restrict__ Wl,
    const float* __restrict__ Wo,
    ushort_t* __restrict__ qkvT, ushort_t* __restrict__ wlT,
    ushort_t* __restrict__ woT, ushort_t* __restrict__ xbf)
{
  int idx = blockIdx.x*256 + threadIdx.x;
  if(idx < 147456){
    int n = idx/192, kk = idx%192;
    const float* W = (n < 256) ? Wq : ((n < 512) ? Wk : Wv);
    qkvT[idx] = f2bf(W[kk*256 + (n & 255)]);
  } else if(idx < 147456 + 589824){
    int t2 = idx - 147456;
    int j   = t2 & 7;
    int sl  = (t2 >> 3) & 3;
    int col = (t2 >> 5) & 255;
    int ks  = (t2 >> 13) & 7;
    int tap = t2 >> 16;
    int grp = sl ^ ((col>>1)&3);
    int k = ks*32 + grp*8 + j;
    wlT[t2] = f2bf(Wl[((size_t)tap*256 + k)*256 + col]);
  } else if(idx < 737280 + 49152){
    int t3 = idx - 737280;
    int col = t3/256, kk = t3%256;
    woT[t3] = f2bf(Wo[kk*192 + col]);
  } else {
    int c = idx - 786432;               // chunk id, 100352*24 chunks
    int row = c/24, cp = c%24;
    int sc = cp ^ (row&7);
    const float* src = x + (size_t)row*192 + sc*8;
    float4 f0 = *(const float4*)src;
    float4 f1 = *(const float4*)(src+4);
    u16x8 o;
    o[0]=f2bf(f0.x); o[1]=f2bf(f0.y); o[2]=f2bf(f0.z); o[3]=f2bf(f0.w);
    o[4]=f2bf(f1.x); o[5]=f2bf(f1.y); o[6]=f2bf(f1.z); o[7]=f2bf(f1.w);
    *(u16x8*)&xbf[(size_t)c*8] = o;
  }
}

// ---------------------------------------------------------------- qkv GEMM
// C[100352,256] = X[100352,192] @ W[192,256]  (per which in {q,k,v})
// block: 64px x 256col, 4 waves (1m x 4n), wave 64x64. A staged via linear
// global_load_lds DMA from pre-swizzled xbf; 24 KB LDS -> high occupancy.
__global__ __launch_bounds__(256,4) void qkv_kernel(
    const ushort_t* __restrict__ xbf, const ushort_t* __restrict__ WT,
    ushort_t* __restrict__ q, ushort_t* __restrict__ kbuf,
    ushort_t* __restrict__ vbuf)
{
  __shared__ ushort_t aLds[64*192];     // 24 KB
  const int m0 = blockIdx.x * 64;
  const int which = blockIdx.y;
  ushort_t* O = (which==0) ? q : ((which==1) ? kbuf : vbuf);
  const int tid = threadIdx.x;
  const int l = tid & 63, w = tid >> 6;
  const int lr = l&15, g = l>>4;
  // stage A: pure linear copy (swizzle pre-baked in xbf)
  #pragma unroll
  for(int r=0;r<6;++r){
    gload_lds16(xbf + (size_t)m0*192 + (size_t)(tid + r*256)*8,
                aLds + (size_t)(r*256 + w*64)*8);
  }
  __syncthreads();

  const ushort_t* Wbase = WT + (size_t)(which*256 + w*64)*192;
  f32x4 acc[4][4];
  #pragma unroll
  for(int mi=0;mi<4;++mi)
    #pragma unroll
    for(int nj=0;nj<4;++nj){ f32x4 z={0.f,0.f,0.f,0.f}; acc[mi][nj]=z; }

  bf16x8 bA[4], bB[4];
  #pragma unroll
  for(int nj=0;nj<4;++nj) bA[nj] = ldg_bf8u(Wbase + (size_t)(nj*16+lr)*192 + g*8);

  #pragma unroll
  for(int ks2=0; ks2<3; ++ks2){
    int ks0 = 2*ks2, ks1 = 2*ks2+1;
    #pragma unroll
    for(int nj=0;nj<4;++nj) bB[nj] = ldg_bf8u(Wbase + (size_t)(nj*16+lr)*192 + ks1*32 + g*8);
    #pragma unroll
    for(int mi=0;mi<4;++mi){
      int row = mi*16 + lr;
      bf16x8 af = lds_bf8(&aLds[(row*192 + ks0*32 + g*8) ^ ((row&7)<<3)]);
      #pragma unroll
      for(int nj=0;nj<4;++nj) acc[mi][nj] = MFMA16(af, bA[nj], acc[mi][nj]);
    }
    if(ks2<2){
      #pragma unroll
      for(int nj=0;nj<4;++nj) bA[nj] = ldg_bf8u(Wbase + (size_t)(nj*16+lr)*192 + (ks1+1)*32 + g*8);
    }
    #pragma unroll
    for(int mi=0;mi<4;++mi){
      int row = mi*16 + lr;
      bf16x8 af = lds_bf8(&aLds[(row*192 + ks1*32 + g*8) ^ ((row&7)<<3)]);
      #pragma unroll
      for(int nj=0;nj<4;++nj) acc[mi][nj] = MFMA16(af, bB[nj], acc[mi][nj]);
    }
  }
  #pragma unroll
  for(int mi=0;mi<4;++mi)
    #pragma unroll
    for(int nj=0;nj<4;++nj){
      int col = w*64 + nj*16 + lr;
      #pragma unroll
      for(int i=0;i<4;++i){
        int row = mi*16 + g*4 + i;
        O[(size_t)(m0+row)*256 + col] = f2bf(acc[mi][nj][i]);
      }
    }
}

// ---------------------------------------------------------------- 3x3 conv
// implicit GEMM, 128px x 256ch per block, 4 waves (2m x 2n), wave 64x128.
// 72 phases (ks,tap); B triple-buffered in LDS, A double-buffered;
// counted vmcnt (4/8, never 0 in main loop) + raw s_barrier.
// NOTE (R6 lesson): register-resident B spills to scratch (acc already
// fills the AGPR half) -- B must stay in LDS at this accumulator size.
__global__ __launch_bounds__(256,2) void conv_kernel(
    const ushort_t* __restrict__ v, const ushort_t* __restrict__ WlT,
    const float* __restrict__ b_local, ushort_t* __restrict__ local_out)
{
  __shared__ ushort_t aBuf[2][256*32];   // 2 x 16 KB
  __shared__ ushort_t bBuf[3][256*32];   // 3 x 16 KB
  const int bid = blockIdx.x;
  const int tile = (bid & 7) * 98 + (bid >> 3);   // XCD-contiguous (784 = 8*98)
  const int p0 = tile * 128;
  const int tid = threadIdx.x;
  const int l = tid&63, w=tid>>6, wm=w>>1, wn=w&1, lr=l&15, g=l>>4;

  unsigned maskbits[4];
  int pxloc[4];
  #pragma unroll
  for(int mi=0;mi<4;++mi){
    int p = p0 + wm*64 + mi*16 + lr;
    int rem = p % 3136;
    int y = rem/56, x = rem%56;
    unsigned mb = 0;
    #pragma unroll
    for(int tap=0;tap<9;++tap){
      int dy = tap/3 - 1, dx = tap%3 - 1;
      if(((unsigned)(y+dy) < 56u) && ((unsigned)(x+dx) < 56u)) mb |= (1u<<tap);
    }
    maskbits[mi] = mb;
    pxloc[mi] = wm*64 + mi*16 + lr + 64;
  }

  auto stageA = [&](int ks, ushort_t* dst){
    #pragma unroll
    for(int r=0;r<4;++r){
      int c = tid + r*256;
      int px = c>>2, sl = c&3;
      int px_abs = p0 - 64 + px;
      px_abs = min(max(px_abs, 0), 100351);
      int chunk = sl ^ ((px>>1)&3);
      gload_lds16(v + (size_t)px_abs*256 + ks*32 + chunk*8,
                  dst + (size_t)(r*256 + w*64)*8);
    }
  };
  auto stageB = [&](int ks, int tap, ushort_t* dst){
    const ushort_t* src = WlT + ((size_t)tap*8 + ks)*8192;
    #pragma unroll
    for(int r=0;r<4;++r){
      gload_lds16(src + (size_t)(tid + r*256)*8,
                  dst + (size_t)(r*256 + w*64)*8);
    }
  };

  f32x4 acc[4][8];
  #pragma unroll
  for(int mi=0;mi<4;++mi)
    #pragma unroll
    for(int nj=0;nj<8;++nj){ f32x4 z={0.f,0.f,0.f,0.f}; acc[mi][nj]=z; }

  auto compute = [&](int tap, const ushort_t* aL, const ushort_t* bL){
    int shift = (tap/3 - 1)*56 + (tap%3 - 1);
    bf16x8 af[4];
    #pragma unroll
    for(int mi=0;mi<4;++mi){
      int px = pxloc[mi] + shift;
      int sl = g ^ ((px>>1)&3);
      u16x8 rv = *(const u16x8*)&aL[px*32 + sl*8];
      if(!((maskbits[mi]>>tap)&1)){ u16x8 z={0,0,0,0,0,0,0,0}; rv=z; }
      af[mi] = __builtin_bit_cast(bf16x8, rv);
    }
    __builtin_amdgcn_s_setprio(1);
    #pragma unroll
    for(int nj=0;nj<8;++nj){
      int col = wn*128 + nj*16 + lr;
      int slb = g ^ ((col>>1)&3);
      bf16x8 bfr = lds_bf8(&bL[col*32 + slb*8]);
      #pragma unroll
      for(int mi=0;mi<4;++mi) acc[mi][nj] = MFMA16(af[mi], bfr, acc[mi][nj]);
    }
    __builtin_amdgcn_s_setprio(0);
  };

  stageA(0, aBuf[0]);
  stageB(0, 0, bBuf[0]);
  stageB(0, 1, bBuf[1]);

  for(int ks=0; ks<7; ++ks){
    #pragma unroll
    for(int tap=0; tap<9; ++tap){
      if(tap==1) WAITVM(8); else WAITVM(4);
      BARRIER();
      if(tap==0) stageA(ks+1, aBuf[(ks+1)&1]);
      stageB(ks + (tap+2)/9, (tap+2)%9, bBuf[(tap+2)%3]);
      compute(tap, aBuf[ks&1], bBuf[tap%3]);
    }
  }
  #pragma unroll
  for(int tap=0; tap<9; ++tap){
    if(tap==8) WAITVM(0); else WAITVM(4);
    BARRIER();
    if(tap<7) stageB(7, tap+2, bBuf[(tap+2)%3]);
    compute(tap, aBuf[1], bBuf[tap%3]);
  }

  #pragma unroll
  for(int nj=0;nj<8;++nj){
    int col = wn*128 + nj*16 + lr;
    float bb = b_local[col];
    #pragma unroll
    for(int mi=0;mi<4;++mi)
      #pragma unroll
      for(int i=0;i<4;++i){
        int p = p0 + wm*64 + mi*16 + g*4 + i;
        local_out[(size_t)p*256 + col] = f2bf(acc[mi][nj][i] + bb);
      }
  }
}

// ---------------------------------------------------------------- attention
// one wave per (window, head); 49 padded to 64.
// Epilogue fuses the +local add and writes the SUM buffer with the
// outproj chunk-swizzle pre-baked: sum[pix][(e/8 ^ (pix&7))*8 + e%8].
__global__ __launch_bounds__(256) void attn_kernel(
    const ushort_t* __restrict__ q, const ushort_t* __restrict__ k,
    const ushort_t* __restrict__ v, const ushort_t* __restrict__ locl,
    ushort_t* __restrict__ sum)
{
  __shared__ ushort_t pLds[4*64*64];
  __shared__ ushort_t vLds[4*32*64];
  const int tid = threadIdx.x;
  const int w = tid>>6, l = tid&63, lr = l&15, g = l>>4;
  const int gid = blockIdx.x*4 + w;
  const int win = gid>>3, head = gid&7;
  const int b = win>>6, rem = win&63, wy = rem>>3, wx = rem&7;
  const size_t base = (size_t)b*3136 + wy*7*56 + wx*7;
  ushort_t* pl = pLds + w*4096;
  ushort_t* vl = vLds + w*2048;
  {
    int p = l;
    bool valid = p < 49;
    const ushort_t* vp = v + (base + (p/7)*56 + (p%7))*256 + head*32;
    #pragma unroll
    for(int d0=0; d0<32; d0+=8){
      u16x8 rv = {0,0,0,0,0,0,0,0};
      if(valid) rv = *(const u16x8*)(vp + d0);
      #pragma unroll
      for(int j=0;j<8;++j){
        int d = d0+j;
        vl[(d*64 + p) ^ ((d&7)<<3)] = valid ? rv[j] : (ushort_t)0;
      }
    }
  }
  f32x4 dot[4][4];
  #pragma unroll
  for(int mi=0;mi<4;++mi)
    #pragma unroll
    for(int nj=0;nj<4;++nj){ f32x4 z={0.f,0.f,0.f,0.f}; dot[mi][nj]=z; }
  bf16x8 qf[4], kf[4];
  #pragma unroll
  for(int t=0;t<4;++t){
    int p = t*16 + lr; bool valid = p<49;
    size_t pix = base + (p/7)*56 + (p%7);
    qf[t] = ldg_bf8(q + pix*256 + head*32 + g*8, valid);
    kf[t] = ldg_bf8(k + pix*256 + head*32 + g*8, valid);
  }
  #pragma unroll
  for(int mi=0;mi<4;++mi)
    #pragma unroll
    for(int nj=0;nj<4;++nj)
      dot[mi][nj] = MFMA16(qf[mi], kf[nj], dot[mi][nj]);
  const float sc = 0.17677669529663687f * 1.4426950408889634f;
  float rs[4][4];
  #pragma unroll
  for(int mi=0;mi<4;++mi){
    #pragma unroll
    for(int i=0;i<4;++i){
      float m = -1e30f;
      #pragma unroll
      for(int nj=0;nj<4;++nj){
        int col = nj*16 + lr;
        if(col < 49) m = fmaxf(m, dot[mi][nj][i]);
      }
      m = fmaxf(m, __shfl_xor(m,1));
      m = fmaxf(m, __shfl_xor(m,2));
      m = fmaxf(m, __shfl_xor(m,4));
      m = fmaxf(m, __shfl_xor(m,8));
      float e[4]; float s = 0.f;
      #pragma unroll
      for(int nj=0;nj<4;++nj){
        int col = nj*16 + lr;
        e[nj] = (col < 49) ? exp2f((dot[mi][nj][i]-m)*sc) : 0.f;
        s += e[nj];
      }
      s += __shfl_xor(s,1); s += __shfl_xor(s,2);
      s += __shfl_xor(s,4); s += __shfl_xor(s,8);
      rs[mi][i] = s;
      int row = mi*16 + g*4 + i;
      #pragma unroll
      for(int nj=0;nj<4;++nj){
        int col = nj*16 + lr;
        pl[(row*64 + col) ^ ((row&7)<<3)] = f2bf(e[nj]);
      }
    }
  }
  __syncthreads();
  f32x4 o[4][2];
  #pragma unroll
  for(int mi=0;mi<4;++mi)
    #pragma unroll
    for(int nj=0;nj<2;++nj){ f32x4 z={0.f,0.f,0.f,0.f}; o[mi][nj]=z; }
  #pragma unroll
  for(int ks=0;ks<2;++ks){
    bf16x8 pa[4];
    #pragma unroll
    for(int mi=0;mi<4;++mi){
      int row = mi*16 + lr;
      pa[mi] = lds_bf8(&pl[(row*64 + ks*32 + g*8) ^ ((row&7)<<3)]);
    }
    #pragma unroll
    for(int nj=0;nj<2;++nj){
      int d = nj*16 + lr;
      bf16x8 vb = lds_bf8(&vl[(d*64 + ks*32 + g*8) ^ ((d&7)<<3)]);
      #pragma unroll
      for(int mi=0;mi<4;++mi) o[mi][nj] = MFMA16(pa[mi], vb, o[mi][nj]);
    }
  }
  #pragma unroll
  for(int mi=0;mi<4;++mi){
    #pragma unroll
    for(int i=0;i<4;++i){
      int row = mi*16 + g*4 + i;
      if(row < 49){
        size_t pix = base + (row/7)*56 + (row%7);
        float inv = 1.0f / rs[mi][i];
        int swz = (int)(pix & 7);
        #pragma unroll
        for(int nj=0;nj<2;++nj){
          int e = head*32 + nj*16 + lr;
          float val = o[mi][nj][i] * inv + bf2f(locl[pix*256 + e]);
          int es = (((e>>3) ^ swz)<<3) | (e & 7);
          sum[pix*256 + es] = f2bf(val);
        }
      }
    }
  }
}

// ---------------------------------------------------------------- out proj
// out[100352,192] = sum[100352,256] @ Wout[256,192] + b_out
// qkv-style: 64px x 192col blocks, 4 waves (1m x 4n), wave 64x48.
// A staged via linear global_load_lds from pre-swizzled sum.
__global__ __launch_bounds__(256,4) void outproj_kernel(
    const ushort_t* __restrict__ sum, const ushort_t* __restrict__ WoT,
    const float* __restrict__ b_out, float* __restrict__ out)
{
  __shared__ ushort_t aLds[64*256];   // 32 KB
  const int m0 = blockIdx.x * 64;
  const int tid = threadIdx.x;
  const int l = tid&63, w = tid>>6, lr=l&15, g=l>>4;
  #pragma unroll
  for(int r=0;r<8;++r){
    gload_lds16(sum + (size_t)m0*256 + (size_t)(tid + r*256)*8,
                aLds + (size_t)(r*256 + w*64)*8);
  }
  __syncthreads();

  const ushort_t* Wbase = WoT + (size_t)(w*48)*256;
  f32x4 acc[4][3];
  #pragma unroll
  for(int mi=0;mi<4;++mi)
    #pragma unroll
    for(int nj=0;nj<3;++nj){ f32x4 z={0.f,0.f,0.f,0.f}; acc[mi][nj]=z; }

  #pragma unroll
  for(int ks=0;ks<8;++ks){
    bf16x8 bfr[3];
    #pragma unroll
    for(int nj=0;nj<3;++nj)
      bfr[nj] = ldg_bf8u(Wbase + (size_t)(nj*16+lr)*256 + ks*32 + g*8);
    bf16x8 af[4];
    #pragma unroll
    for(int mi=0;mi<4;++mi){
      int row = mi*16 + lr;
      af[mi] = lds_bf8(&aLds[(row*256 + ks*32 + g*8) ^ ((row&7)<<3)]);
    }
    #pragma unroll
    for(int nj=0;nj<3;++nj)
      #pragma unroll
      for(int mi=0;mi<4;++mi) acc[mi][nj] = MFMA16(af[mi], bfr[nj], acc[mi][nj]);
  }
  #pragma unroll
  for(int nj=0;nj<3;++nj){
    int col = w*48 + nj*16 + lr;
    float bb = b_out[col];
    #pragma unroll
    for(int mi=0;mi<4;++mi)
      #pragma unroll
      for(int i=0;i<4;++i){
        int row = mi*16 + g*4 + i;
        out[(size_t)(m0+row)*192 + col] = acc[mi][nj][i] + bb;
      }
  }
}

extern "C" void kernel_launch(void* const* d_in, const int* in_sizes, int n_in,
                              void* d_out, int out_size, void* d_ws, size_t ws_size,
                              hipStream_t stream)
{
  const float* x  = (const float*)d_in[0];
  const float* Wq = (const float*)d_in[1];
  const float* Wk = (const float*)d_in[2];
  const float* Wv = (const float*)d_in[3];
  const float* Wl = (const float*)d_in[4];
  const float* bl = (const float*)d_in[5];
  const float* Wo = (const float*)d_in[6];
  const float* bo = (const float*)d_in[7];
  float* out = (float*)d_out;
  char* ws = (char*)d_ws;
  ushort_t* q    = (ushort_t*)(ws);
  ushort_t* kbuf = (ushort_t*)(ws + 51380224);
  ushort_t* vbuf = (ushort_t*)(ws + 102760448);
  ushort_t* sum  = (ushort_t*)(ws + 154140672);  // also xbf (dead before attn_kernel)
  ushort_t* locl = (ushort_t*)(ws + 205520896);
  ushort_t* qkvT = (ushort_t*)(ws + 256901120);
  ushort_t* wlT  = (ushort_t*)(ws + 257196032);
  ushort_t* woT  = (ushort_t*)(ws + 258375680);
  ushort_t* xbf  = sum;   // 38.5 MB < 51.4 MB slot

  prep_kernel<<<12480, 256, 0, stream>>>(x, Wq, Wk, Wv, Wl, Wo, qkvT, wlT, woT, xbf);
  qkv_kernel<<<dim3(1568,3), 256, 0, stream>>>(xbf, qkvT, q, kbuf, vbuf);
  conv_kernel<<<784, 256, 0, stream>>>(vbuf, wlT, bl, locl);
  attn_kernel<<<4096, 256, 0, stream>>>(q, kbuf, vbuf, locl, sum);
  outproj_kernel<<<1568, 256, 0, stream>>>(sum, woT, bo, out);
}